// Round 9
// baseline (50.047 us; speedup 1.0000x reference)
//
#include <hip/hip_runtime.h>

// Problem constants (reference: B=1, T=2048, H=32, D=64, SCALE=1/64, DEG=2)
#define T_DIM 2048
#define H_DIM 32
#define D_DIM 64
#define SCALE_F 0.015625f
#define ROWSTRIDE 2048      // H_DIM * D_DIM floats per t-row

typedef unsigned short ushort;
typedef __attribute__((ext_vector_type(8))) short short8;   // 8 bf16
typedef __attribute__((ext_vector_type(16))) float f32x16;  // 32x32 MFMA acc
typedef __attribute__((ext_vector_type(2))) float f32x2;
typedef __attribute__((ext_vector_type(4))) float f32x4;

#define MFMA32(A, B, C) __builtin_amdgcn_mfma_f32_32x32x16_bf16((A), (B), (C), 0, 0, 0)

// ---------------------------------------------------------------------------
// Kernel 1: per-head inclusive cumsum of g over T -> gc stored [H][T]  (B=1)
// ---------------------------------------------------------------------------
__global__ __launch_bounds__(256)
void cumsum_g_kernel(const float* __restrict__ g, float* __restrict__ gc) {
    const int h = blockIdx.x;
    const int tid = threadIdx.x;
    const int PER = T_DIM / 256;        // 8

    __shared__ float sums[256];

    float loc[8];
    float run = 0.f;
    const int t0 = tid * PER;
    for (int i = 0; i < PER; ++i) {
        run += g[(size_t)(t0 + i) * H_DIM + h];
        loc[i] = run;
    }
    sums[tid] = run;
    __syncthreads();

    for (int off = 1; off < 256; off <<= 1) {
        float vv = (tid >= off) ? sums[tid - off] : 0.f;
        __syncthreads();
        sums[tid] += vv;
        __syncthreads();
    }
    float excl = (tid == 0) ? 0.f : sums[tid - 1];

    for (int i = 0; i < PER; ++i)
        gc[(size_t)h * T_DIM + t0 + i] = excl + loc[i];
}

// ---------------------------------------------------------------------------
// Helpers
// ---------------------------------------------------------------------------
__device__ __forceinline__ short8 ld8(const ushort* p) {
    return *reinterpret_cast<const short8*>(p);
}

__device__ __forceinline__ unsigned cvt_pk_bf16(float lo, float hi) {
    unsigned r;
    asm("v_cvt_pk_bf16_f32 %0, %1, %2" : "=v"(r) : "v"(lo), "v"(hi));
    return r;
}

// Pack 8 f32 W-values (4 f32x2 pairs, C-layout half) into the PV A-operand
// fragment via cvt_pk + permlane32_swap. (Layout verified R3-R8.)
__device__ __forceinline__ short8 pack_w2(const f32x2* w2) {
    unsigned p0 = cvt_pk_bf16(w2[0][0], w2[0][1]);
    unsigned p1 = cvt_pk_bf16(w2[1][0], w2[1][1]);
    unsigned p2 = cvt_pk_bf16(w2[2][0], w2[2][1]);
    unsigned p3 = cvt_pk_bf16(w2[3][0], w2[3][1]);
    asm("v_permlane32_swap_b32 %0, %1" : "+v"(p0), "+v"(p2));
    asm("v_permlane32_swap_b32 %0, %1" : "+v"(p1), "+v"(p3));
    union { unsigned u[4]; short8 s; } af;
    af.u[0] = p0; af.u[1] = p1; af.u[2] = p2; af.u[3] = p3;
    return af.s;
}

// One 32s x 32q unit from LDS frag tiles. MODE 0: full, 1: diag (s<=l31).
// K tile: [ks4][hi2][l31][8]; V tile: [dblk2][kh2 2][hi2][l31][8]. (Verified.)
template<int MODE>
__device__ __forceinline__ void unit32(
    const ushort* ldsK, const ushort* ldsV,
    int lofs, int hi, int l31,
    const short8 (&qr)[4], f32x16& o0, f32x16& o1, f32x2& den2)
{
    const short8 kf0 = ld8(ldsK + lofs);
    const short8 kf1 = ld8(ldsK + 512 + lofs);
    const short8 kf2 = ld8(ldsK + 1024 + lofs);
    const short8 kf3 = ld8(ldsK + 1536 + lofs);
    const short8 vf0 = ld8(ldsV + lofs);           // dblk0 kh2=0
    const short8 vf1 = ld8(ldsV + 512 + lofs);     // dblk0 kh2=1
    const short8 vf2 = ld8(ldsV + 1024 + lofs);    // dblk1 kh2=0
    const short8 vf3 = ld8(ldsV + 1536 + lofs);    // dblk1 kh2=1

    f32x16 c;
#pragma unroll
    for (int i = 0; i < 16; ++i) c[i] = 0.f;
    c = MFMA32(kf0, qr[0], c);
    c = MFMA32(kf1, qr[1], c);
    c = MFMA32(kf2, qr[2], c);
    c = MFMA32(kf3, qr[3], c);

    f32x2 w2[8];
#pragma unroll
    for (int i = 0; i < 8; ++i) {
        const int r0 = 2 * i;
        f32x2 x; x[0] = c[r0]; x[1] = c[r0 + 1];
        f32x2 ww = x * x;
        if (MODE == 1) {
            const int sl0 = (r0 & 3) + 8 * (r0 >> 2) + 4 * hi;
            ww[0] = (sl0 <= l31) ? ww[0] : 0.f;
            ww[1] = (sl0 + 1 <= l31) ? ww[1] : 0.f;
        }
        w2[i] = ww;
        den2 += ww;
    }
    const short8 a0 = pack_w2(&w2[0]);     // kh2 = 0
    o0 = MFMA32(a0, vf0, o0);
    o1 = MFMA32(a0, vf2, o1);
    const short8 a1 = pack_w2(&w2[4]);     // kh2 = 1
    o0 = MFMA32(a1, vf1, o0);
    o1 = MFMA32(a1, vf3, o1);
}

// ---------------------------------------------------------------------------
// Fused staging: fp32 global -> (decay-scaled) bf16 frag layout in LDS.
// Period = 64 s-rows. K: 512 thr x 8 floats (one hi-half of one row).
// V: 512 thr x 8 scalar floats (one frag chunk), lanes coalesced over d.
// ---------------------------------------------------------------------------
struct KStage { f32x4 a, b; float g; };
struct VStage { float v0, v1, v2, v3, v4, v5, v6, v7; };

__device__ __forceinline__ void issue_k(KStage& s, const float* kg,
                                        const float* gch, int s0, int tid) {
    const int r  = tid >> 3;            // 0..63
    const int d0 = (tid & 7) * 8;
    const float* p = kg + (size_t)(s0 + r) * ROWSTRIDE + d0;
    s.a = *reinterpret_cast<const f32x4*>(p);
    s.b = *reinterpret_cast<const f32x4*>(p + 4);
    s.g = gch[s0 + r];
}

__device__ __forceinline__ void write_k(const KStage& s, ushort* bufK, int tid) {
    const int r  = tid >> 3;
    const int ks = (tid & 7) >> 1;
    const int hh = tid & 1;
    const float ek = __expf(-0.5f * s.g);
    union { unsigned u[4]; short8 s8; } o;
    o.u[0] = cvt_pk_bf16(s.a[0] * ek, s.a[1] * ek);
    o.u[1] = cvt_pk_bf16(s.a[2] * ek, s.a[3] * ek);
    o.u[2] = cvt_pk_bf16(s.b[0] * ek, s.b[1] * ek);
    o.u[3] = cvt_pk_bf16(s.b[2] * ek, s.b[3] * ek);
    *reinterpret_cast<short8*>(bufK + (r >> 5) * 2048 + ks * 512 + hh * 256
                               + (r & 31) * 8) = o.s8;
}

__device__ __forceinline__ void issue_v(VStage& s, const float* vg, int s0, int tid) {
    const int c = tid >> 5, l31 = tid & 31;
    const int tile = c >> 3, dblk = (c >> 2) & 1, kh2 = (c >> 1) & 1, hiv = c & 1;
    const int tb = s0 + tile * 32 + kh2 * 16 + hiv * 8;
    const float* p = vg + (size_t)tb * ROWSTRIDE + dblk * 32 + l31;
    s.v0 = p[0 * ROWSTRIDE]; s.v1 = p[1 * ROWSTRIDE];
    s.v2 = p[2 * ROWSTRIDE]; s.v3 = p[3 * ROWSTRIDE];
    s.v4 = p[4 * ROWSTRIDE]; s.v5 = p[5 * ROWSTRIDE];
    s.v6 = p[6 * ROWSTRIDE]; s.v7 = p[7 * ROWSTRIDE];
}

__device__ __forceinline__ void write_v(const VStage& s, ushort* bufV, int tid) {
    const int c = tid >> 5, l31 = tid & 31;
    const int tile = c >> 3;
    const int c3 = c & 7;     // dblk*4 + kh2*2 + hiv
    union { unsigned u[4]; short8 s8; } o;
    o.u[0] = cvt_pk_bf16(s.v0, s.v1);
    o.u[1] = cvt_pk_bf16(s.v2, s.v3);
    o.u[2] = cvt_pk_bf16(s.v4, s.v5);
    o.u[3] = cvt_pk_bf16(s.v6, s.v7);
    *reinterpret_cast<short8*>(bufV + tile * 2048 + c3 * 256 + l31 * 8) = o.s8;
}

// ---------------------------------------------------------------------------
// Kernel 2: fused retention. Grid 512 = 16 ranks x 32 heads; QB = 15-rank
// (LPT: longest blocks dispatched first). 512 threads, 8 waves:
// qi = w&3 -> q-sub (32 rows), si = w>>2 -> s-parity (split-K over periods).
// Period = 64 s-rows staged fp32->bf16 frags (T14 split), dbuf, 1 barrier.
// ---------------------------------------------------------------------------
__global__ __launch_bounds__(512, 4)
void retention_fused_kernel(const float* __restrict__ q,
                            const float* __restrict__ k,
                            const float* __restrict__ v,
                            const float* __restrict__ gc,
                            float* __restrict__ out) {
    __shared__ ushort buf[2][8192];     // [cur][K:4096 | V:4096] = 2 x 16KB
    __shared__ float pmd[8 * 32];       // per (qi,si) denominators

    const int bid = blockIdx.x;
    const int h   = bid & 31;           // h%8 == bid%8 -> head-home XCD
    const int QB  = 15 - (bid >> 5);    // longest first (LPT)

    const int tid = threadIdx.x;
    const int w   = tid >> 6;
    const int qi  = w & 3;
    const int si  = w >> 2;
    const int lane = tid & 63;
    const int hi  = lane >> 5;
    const int l31 = lane & 31;
    const int lofs = hi * 256 + l31 * 8;
    const int myT32 = 4 * QB + qi;

    const float* gch = gc + (size_t)h * T_DIM;
    const float* kg  = k + h * 64;
    const float* vg  = v + h * 64;

    // ---- Q frags from global (once): q̂ = q * SCALE * exp(gc_t/2) ----
    short8 qr[4];
    {
        const int t = myT32 * 32 + l31;
        const float eq = SCALE_F * __expf(0.5f * gch[t]);
        const float* qrow = q + (size_t)t * ROWSTRIDE + h * 64 + hi * 8;
#pragma unroll
        for (int ks = 0; ks < 4; ++ks) {
            f32x4 fa = *reinterpret_cast<const f32x4*>(qrow + ks * 16);
            f32x4 fb = *reinterpret_cast<const f32x4*>(qrow + ks * 16 + 4);
            union { unsigned u[4]; short8 s8; } o;
            o.u[0] = cvt_pk_bf16(fa[0] * eq, fa[1] * eq);
            o.u[1] = cvt_pk_bf16(fa[2] * eq, fa[3] * eq);
            o.u[2] = cvt_pk_bf16(fb[0] * eq, fb[1] * eq);
            o.u[3] = cvt_pk_bf16(fb[2] * eq, fb[3] * eq);
            qr[ks] = o.s8;
        }
    }

    f32x16 o0, o1;
#pragma unroll
    for (int i = 0; i < 16; ++i) { o0[i] = 0.f; o1[i] = 0.f; }
    f32x2 d2; d2[0] = 0.f; d2[1] = 0.f;

    const int NJ = 2 * QB + 2;          // 64-s periods

    // prologue: stage period 0
    KStage kst; VStage vst;
    issue_k(kst, kg, gch, 0, tid);
    issue_v(vst, vg, 0, tid);
    write_k(kst, buf[0], tid);
    write_v(vst, buf[0] + 4096, tid);
    __syncthreads();

    for (int J = 0; J < NJ; ++J) {
        const int cur = J & 1;
        if (J + 1 < NJ) {               // issue next period's loads early
            issue_k(kst, kg, gch, (J + 1) * 64, tid);
            issue_v(vst, vg, (J + 1) * 64, tid);
        }
        const ushort* bK = buf[cur];
        const ushort* bV = buf[cur] + 4096;
        const int c1 = 2 * J + si;      // s-subtile (t32 units) for this wave

        if (c1 < myT32)
            unit32<0>(bK + si * 2048, bV + si * 2048, lofs, hi, l31, qr, o0, o1, d2);
        else if (c1 == myT32)
            unit32<1>(bK + si * 2048, bV + si * 2048, lofs, hi, l31, qr, o0, o1, d2);

        if (J + 1 < NJ) {               // latency hidden under compute
            write_k(kst, buf[cur ^ 1], tid);
            write_v(vst, buf[cur ^ 1] + 4096, tid);
        }
        __syncthreads();                // writes visible; reads of cur done
    }

    // ---- epilogue: merge si-partials in (now free) staging LDS ----
    float* pm = (float*)&buf[0][0];     // 32KB: [qi][row32][col64]

    float den = d2[0] + d2[1];
    den += __shfl_xor(den, 32);
    if (hi == 0) pmd[(qi * 2 + si) * 32 + l31] = den;

    if (si == 0) {
#pragma unroll
        for (int rr = 0; rr < 16; ++rr) {
            const int row = (rr & 3) + 8 * (rr >> 2) + 4 * hi;
            pm[(qi * 32 + row) * 64 + l31]      = o0[rr];
            pm[(qi * 32 + row) * 64 + 32 + l31] = o1[rr];
        }
    }
    __syncthreads();
    if (si == 1) {
#pragma unroll
        for (int rr = 0; rr < 16; ++rr) {
            const int row = (rr & 3) + 8 * (rr >> 2) + 4 * hi;
            pm[(qi * 32 + row) * 64 + l31]      += o0[rr];
            pm[(qi * 32 + row) * 64 + 32 + l31] += o1[rr];
        }
    }
    __syncthreads();

    // final write: 512 threads -> 128 rows x 64 cols
    {
        const int row  = tid >> 2;          // 0..127
        const int qq   = row >> 5;
        const int r32  = row & 31;
        const int dseg = (tid & 3) * 16;
        const float dtot = pmd[(qq * 2 + 0) * 32 + r32]
                         + pmd[(qq * 2 + 1) * 32 + r32];
        const float inv = 1.f / fmaxf(dtot, 1.f);
        const float* src = pm + (qq * 32 + r32) * 64 + dseg;
        float* dst = out + ((size_t)(QB * 128 + row) * H_DIM + h) * 64 + dseg;
#pragma unroll
        for (int jv = 0; jv < 4; ++jv) {
            f32x4 s = *reinterpret_cast<const f32x4*>(src + 4 * jv);
            s *= inv;
            *reinterpret_cast<f32x4*>(dst + 4 * jv) = s;
        }
    }
}

// ---------------------------------------------------------------------------
extern "C" void kernel_launch(void* const* d_in, const int* in_sizes, int n_in,
                              void* d_out, int out_size, void* d_ws, size_t ws_size,
                              hipStream_t stream) {
    const float* q = (const float*)d_in[0];
    const float* k = (const float*)d_in[1];
    const float* v = (const float*)d_in[2];
    const float* g = (const float*)d_in[3];
    float* out = (float*)d_out;

    float* gc = (float*)d_ws;   // H*T floats = 256 KB

    cumsum_g_kernel<<<H_DIM, 256, 0, stream>>>(g, gc);
    retention_fused_kernel<<<512, 512, 0, stream>>>(q, k, v, gc, out);
}